// Round 3
// baseline (324.592 us; speedup 1.0000x reference)
//
#include <hip/hip_runtime.h>

#define IN_DIM 32
#define OUT_DIM 64
#define NB_SCAN 391  // ceil(100000/256); scan2 pads to 512

// K1: histogram of dst. 1.6M global atomics over 100K counters.
__global__ __launch_bounds__(256) void hist_kernel(
    const int* __restrict__ dst, int* __restrict__ counts, int n_edges) {
    int e = blockIdx.x * 256 + threadIdx.x;
    if (e < n_edges) atomicAdd(&counts[dst[e]], 1);
}

// K2: per-block exclusive scan (Hillis-Steele in LDS), writes block sums.
__global__ __launch_bounds__(256) void scan1_kernel(
    const int* __restrict__ counts, int* __restrict__ row_start,
    int* __restrict__ block_sums, int n) {
    __shared__ int tmp[256];
    int tx = threadIdx.x;
    int idx = blockIdx.x * 256 + tx;
    int v = (idx < n) ? counts[idx] : 0;
    tmp[tx] = v;
    __syncthreads();
    for (int off = 1; off < 256; off <<= 1) {
        int t = (tx >= off) ? tmp[tx - off] : 0;
        __syncthreads();
        tmp[tx] += t;
        __syncthreads();
    }
    if (idx < n) row_start[idx] = tmp[tx] - v;  // exclusive
    if (tx == 255) block_sums[blockIdx.x] = tmp[255];
}

// K3: exclusive scan of the 391 block sums, one block of 512 threads.
__global__ __launch_bounds__(512) void scan2_kernel(int* __restrict__ block_sums, int nb) {
    __shared__ int tmp[512];
    int tx = threadIdx.x;
    int v = (tx < nb) ? block_sums[tx] : 0;
    tmp[tx] = v;
    __syncthreads();
    for (int off = 1; off < 512; off <<= 1) {
        int t = (tx >= off) ? tmp[tx - off] : 0;
        __syncthreads();
        tmp[tx] += t;
        __syncthreads();
    }
    if (tx < nb) block_sums[tx] = tmp[tx] - v;  // exclusive
}

// K4: add block offsets in place; copy to cursor; write sentinel.
__global__ __launch_bounds__(256) void finalize_kernel(
    int* __restrict__ row_start, const int* __restrict__ block_sums,
    int* __restrict__ cursor, int n, int n_edges) {
    int idx = blockIdx.x * 256 + threadIdx.x;
    if (idx < n) {
        int v = row_start[idx] + block_sums[blockIdx.x];
        row_start[idx] = v;
        cursor[idx] = v;
    }
    if (blockIdx.x == 0 && threadIdx.x == 0) row_start[n] = n_edges;
}

// K5: scatter src ids into dst-sorted order. 1.6M atomics for positions.
__global__ __launch_bounds__(256) void scatter_kernel(
    const int* __restrict__ src, const int* __restrict__ dst,
    int* __restrict__ cursor, int* __restrict__ edge_src, int n_edges) {
    int e = blockIdx.x * 256 + threadIdx.x;
    if (e < n_edges) {
        int pos = atomicAdd(&cursor[dst[e]], 1);
        edge_src[pos] = src[e];
    }
}

// K6: fused gather + projection. 8 nodes/block; 32 lanes per node hold the
// 32-dim accumulator (1 f32/lane). Edge ids broadcast within the half-wave;
// feature row reads are 128B coalesced, LLC-resident. Then stage h rows in
// LDS and project through LDS-staged W (64 consecutive cols/wave -> 2
// lanes/bank, free), writing out directly — no h round-trip.
__global__ __launch_bounds__(256) void gather_proj_kernel(
    const float* __restrict__ feature, const int* __restrict__ row_start,
    const int* __restrict__ edge_src, const float* __restrict__ W,
    const float* __restrict__ b, float* __restrict__ out, int n_nodes) {
    __shared__ float Ws[IN_DIM * OUT_DIM];
    __shared__ float bs[OUT_DIM];
    __shared__ float hs[8][IN_DIM];
    int tx = threadIdx.x;

    for (int i = tx; i < IN_DIM * OUT_DIM; i += 256) Ws[i] = W[i];
    if (tx < OUT_DIM) bs[tx] = b[tx];

    int slot = tx >> 5, lane = tx & 31;
    int node = blockIdx.x * 8 + slot;
    float acc = 0.0f;
    if (node < n_nodes) {
        int s0 = row_start[node], s1 = row_start[node + 1];
        int i = s0;
        for (; i + 4 <= s1; i += 4) {  // 4-deep MLP on the row fetches
            int ea = edge_src[i], eb = edge_src[i + 1];
            int ec = edge_src[i + 2], ed = edge_src[i + 3];
            float fa = feature[(long long)ea * IN_DIM + lane];
            float fb = feature[(long long)eb * IN_DIM + lane];
            float fc = feature[(long long)ec * IN_DIM + lane];
            float fd = feature[(long long)ed * IN_DIM + lane];
            acc += fa + fb + fc + fd;
        }
        for (; i < s1; ++i) acc += feature[(long long)edge_src[i] * IN_DIM + lane];
    }
    hs[slot][lane] = acc;
    __syncthreads();

    int node0 = blockIdx.x * 8;
#pragma unroll
    for (int it = 0; it < 2; ++it) {
        int idx = tx + it * 256;       // 512 (slot,col) items, 2 per thread
        int sl = idx >> 6, col = idx & 63;
        int n2 = node0 + sl;
        if (n2 >= n_nodes) continue;
        float a = bs[col];
#pragma unroll
        for (int k = 0; k < IN_DIM; ++k) a += hs[sl][k] * Ws[k * OUT_DIM + col];
        out[(long long)n2 * OUT_DIM + col] = a;
    }
}

extern "C" void kernel_launch(void* const* d_in, const int* in_sizes, int n_in,
                              void* d_out, int out_size, void* d_ws, size_t ws_size,
                              hipStream_t stream) {
    const float* feature = (const float*)d_in[0];
    const int* src = (const int*)d_in[1];
    const int* dst = (const int*)d_in[2];
    const float* W = (const float*)d_in[3];
    const float* b = (const float*)d_in[4];
    float* out = (float*)d_out;

    int n_nodes = in_sizes[0] / IN_DIM;  // 100000
    int n_edges = in_sizes[1];           // 1600000

    // Workspace layout (all int32, 4B aligned): ~8 MB total.
    int* counts = (int*)d_ws;                   // n_nodes
    int* row_start = counts + n_nodes;          // n_nodes + 1
    int* cursor = row_start + n_nodes + 1;      // n_nodes
    int* block_sums = cursor + n_nodes;         // 512 (padded)
    int* edge_src = block_sums + 512;           // n_edges

    (void)hipMemsetAsync(counts, 0, (size_t)n_nodes * sizeof(int), stream);

    int eb = (n_edges + 255) / 256;
    int nb = (n_nodes + 255) / 256;  // 391
    hist_kernel<<<eb, 256, 0, stream>>>(dst, counts, n_edges);
    scan1_kernel<<<nb, 256, 0, stream>>>(counts, row_start, block_sums, n_nodes);
    scan2_kernel<<<1, 512, 0, stream>>>(block_sums, nb);
    finalize_kernel<<<nb, 256, 0, stream>>>(row_start, block_sums, cursor, n_nodes, n_edges);
    scatter_kernel<<<eb, 256, 0, stream>>>(src, dst, cursor, edge_src, n_edges);

    int gblocks = (n_nodes + 7) / 8;
    gather_proj_kernel<<<gblocks, 256, 0, stream>>>(feature, row_start, edge_src, W, b, out, n_nodes);
}